// Round 1
// baseline (1021.088 us; speedup 1.0000x reference)
//
#include <hip/hip_runtime.h>

typedef short bf16x8 __attribute__((ext_vector_type(8)));
typedef float f32x4 __attribute__((ext_vector_type(4)));

__device__ __forceinline__ float b2f(unsigned short u) {
  union { unsigned int i; float f; } x; x.i = ((unsigned int)u) << 16; return x.f;
}
__device__ __forceinline__ unsigned short f2b(float f) {
  union { float f; unsigned int u; } x; x.f = f;
  unsigned int r = (x.u + 0x7FFFu + ((x.u >> 16) & 1u)) >> 16;
  return (unsigned short)r;
}
__device__ __forceinline__ float gelu_f(float v) {
  return 0.5f * v * (1.0f + erff(v * 0.70710678118654752440f));
}

// ------------------- setup kernels -------------------

__global__ void count_kernel(const int* __restrict__ ei, int E, int* __restrict__ cnt) {
  int e = blockIdx.x * 256 + threadIdx.x;
  if (e < E) atomicAdd(&cnt[ei[E + e]], 1);
}

__global__ void dinv_kernel(const int* __restrict__ cnt, float* __restrict__ dinv, int Nn) {
  int n = blockIdx.x * 256 + threadIdx.x;
  if (n < Nn) dinv[n] = rsqrtf((float)cnt[n] + 1.0f);  // +1 self-loop
}

__global__ __launch_bounds__(1024) void scan_kernel(const int* __restrict__ cnt,
                                                    int* __restrict__ rowstart,
                                                    int* __restrict__ cursor, int Nn) {
  __shared__ int part[1024];
  int t = threadIdx.x;
  int CH = (Nn + 1023) >> 10;
  int b0 = t * CH;
  int s = 0;
  for (int i = 0; i < CH; ++i) { int idx = b0 + i; if (idx < Nn) s += cnt[idx]; }
  part[t] = s;
  __syncthreads();
  for (int d = 1; d < 1024; d <<= 1) {
    int v = part[t];
    int add = (t >= d) ? part[t - d] : 0;
    __syncthreads();
    part[t] = v + add;
    __syncthreads();
  }
  int run = (t == 0) ? 0 : part[t - 1];
  for (int i = 0; i < CH; ++i) {
    int idx = b0 + i;
    if (idx < Nn) { rowstart[idx] = run; cursor[idx] = run; run += cnt[idx]; }
  }
  if (t == 1023) rowstart[Nn] = part[1023];
}

__global__ void fill_kernel(const int* __restrict__ ei, int E, const float* __restrict__ dinv,
                            int* __restrict__ cursor, int* __restrict__ ssrc,
                            float* __restrict__ snorm) {
  int e = blockIdx.x * 256 + threadIdx.x;
  if (e < E) {
    int s = ei[e], d = ei[E + e];
    int pos = atomicAdd(&cursor[d], 1);
    ssrc[pos] = s;
    snorm[pos] = dinv[s] * dinv[d];
  }
}

// W (K x N, f32, row-major) -> WT (N x K, bf16, row-major)
__global__ void wtrans_kernel(const float* __restrict__ W, unsigned short* __restrict__ WT,
                              int K, int N) {
  int i = blockIdx.x * 256 + threadIdx.x;
  if (i < K * N) {
    int n = i / K, k = i - n * K;
    WT[i] = f2b(W[k * N + n]);
  }
}

// ------------------- aggregation: out[n] = dinv[n]^2*in[n] + sum_e norm_e*in[src_e] -------------------
// one wave per node; V = F/64 elems per lane

template <int F, bool INF32, bool OUTF32, bool HASBIAS, bool DOGELU>
__global__ __launch_bounds__(256) void agg_kernel(
    const int* __restrict__ rowstart, const int* __restrict__ ssrc,
    const float* __restrict__ snorm, const float* __restrict__ dinv,
    const void* __restrict__ inv, const float* __restrict__ bias,
    void* __restrict__ outv, int Nn) {
  constexpr int V = F / 64;
  const int lane = threadIdx.x & 63;
  const int node = blockIdx.x * 4 + (threadIdx.x >> 6);
  if (node >= Nn) return;
  const int base = lane * V;
  float acc[V];
  {
    float w = dinv[node]; w = w * w;
    if constexpr (INF32) {
      const float* in = (const float*)inv + (size_t)node * F + base;
      if constexpr (V == 2) {
        float2 v = *(const float2*)in; acc[0] = w * v.x; acc[1] = w * v.y;
      } else {
        float4 v0 = *(const float4*)in; float4 v1 = *(const float4*)(in + 4);
        acc[0] = w * v0.x; acc[1] = w * v0.y; acc[2] = w * v0.z; acc[3] = w * v0.w;
        acc[4] = w * v1.x; acc[5] = w * v1.y; acc[6] = w * v1.z; acc[7] = w * v1.w;
      }
    } else {
      const unsigned short* in = (const unsigned short*)inv + (size_t)node * F + base;
      if constexpr (V == 2) {
        unsigned int v = *(const unsigned int*)in;
        acc[0] = w * b2f(v & 0xffffu); acc[1] = w * b2f(v >> 16);
      } else {
        bf16x8 v = *(const bf16x8*)in;
#pragma unroll
        for (int i = 0; i < 8; ++i) acc[i] = w * b2f((unsigned short)v[i]);
      }
    }
  }
  const int e0 = rowstart[node], e1 = rowstart[node + 1];
  for (int e = e0; e < e1; ++e) {
    const int s = ssrc[e];
    const float w = snorm[e];
    if constexpr (INF32) {
      const float* in = (const float*)inv + (size_t)s * F + base;
      if constexpr (V == 2) {
        float2 v = *(const float2*)in; acc[0] += w * v.x; acc[1] += w * v.y;
      } else {
        float4 v0 = *(const float4*)in; float4 v1 = *(const float4*)(in + 4);
        acc[0] += w * v0.x; acc[1] += w * v0.y; acc[2] += w * v0.z; acc[3] += w * v0.w;
        acc[4] += w * v1.x; acc[5] += w * v1.y; acc[6] += w * v1.z; acc[7] += w * v1.w;
      }
    } else {
      const unsigned short* in = (const unsigned short*)inv + (size_t)s * F + base;
      if constexpr (V == 2) {
        unsigned int v = *(const unsigned int*)in;
        acc[0] += w * b2f(v & 0xffffu); acc[1] += w * b2f(v >> 16);
      } else {
        bf16x8 v = *(const bf16x8*)in;
#pragma unroll
        for (int i = 0; i < 8; ++i) acc[i] += w * b2f((unsigned short)v[i]);
      }
    }
  }
  if constexpr (HASBIAS) {
#pragma unroll
    for (int i = 0; i < V; ++i) acc[i] += bias[base + i];
  }
  if constexpr (DOGELU) {
#pragma unroll
    for (int i = 0; i < V; ++i) acc[i] = gelu_f(acc[i]);
  }
  if constexpr (OUTF32) {
    float* out = (float*)outv + (size_t)node * F + base;
#pragma unroll
    for (int i = 0; i < V; ++i) out[i] = acc[i];
  } else {
    unsigned short* out = (unsigned short*)outv + (size_t)node * F + base;
    if constexpr (V == 2) {
      unsigned int pack = (unsigned int)f2b(acc[0]) | ((unsigned int)f2b(acc[1]) << 16);
      *(unsigned int*)out = pack;
    } else {
      bf16x8 o;
#pragma unroll
      for (int i = 0; i < 8; ++i) o[i] = (short)f2b(acc[i]);
      *(bf16x8*)out = o;
    }
  }
}

// ------------------- GEMM: C(M x N) = A(M x K) * BT(N x K)^T  [bf16 in, bf16 out] -------------------
// 128x128 tile, BK=32, 4 waves (2x2 of 64x64), mfma 16x16x32, global_load_lds staging.

template <bool HASBIAS, bool DOGELU>
__global__ __launch_bounds__(256) void gemm_bt(
    const unsigned short* __restrict__ A, const unsigned short* __restrict__ BT,
    const float* __restrict__ bias, unsigned short* __restrict__ C,
    int N, int K) {
  __shared__ alignas(16) unsigned short Asl[128 * 32];
  __shared__ alignas(16) unsigned short Bsl[128 * 32];
  const int tid = threadIdx.x;
  const int lane = tid & 63;
  const int wid = tid >> 6;
  const size_t brow = (size_t)blockIdx.x * 128;
  const size_t bcol = (size_t)blockIdx.y * 128;
  const int wr = (wid >> 1) * 64;
  const int wc = (wid & 1) * 64;
  const int rr = lane & 15, rg = lane >> 4;
  f32x4 acc[4][4] = {};
  const int KT = K >> 5;
  for (int kt = 0; kt < KT; ++kt) {
    const int kb = kt << 5;
#pragma unroll
    for (int rsub = 0; rsub < 2; ++rsub) {
      const int c = tid + rsub * 256;
      const int arow = c >> 2;
      const int acol = (c & 3) << 3;
      const unsigned short* gA = A + (brow + arow) * K + kb + acol;
      __builtin_amdgcn_global_load_lds((const __attribute__((address_space(1))) void*)gA,
                                       (__attribute__((address_space(3))) void*)(&Asl[c * 8]),
                                       16, 0, 0);
      const unsigned short* gB = BT + (bcol + arow) * K + kb + acol;
      __builtin_amdgcn_global_load_lds((const __attribute__((address_space(1))) void*)gB,
                                       (__attribute__((address_space(3))) void*)(&Bsl[c * 8]),
                                       16, 0, 0);
    }
    __syncthreads();
    bf16x8 af[4], bfr[4];
#pragma unroll
    for (int m = 0; m < 4; ++m) af[m] = *(const bf16x8*)(&Asl[(wr + m * 16 + rr) * 32 + rg * 8]);
#pragma unroll
    for (int n = 0; n < 4; ++n) bfr[n] = *(const bf16x8*)(&Bsl[(wc + n * 16 + rr) * 32 + rg * 8]);
#pragma unroll
    for (int m = 0; m < 4; ++m)
#pragma unroll
      for (int n = 0; n < 4; ++n)
        acc[m][n] = __builtin_amdgcn_mfma_f32_16x16x32_bf16(af[m], bfr[n], acc[m][n], 0, 0, 0);
    __syncthreads();
  }
  // C/D layout (m89): col = lane&15, row = 4*(lane>>4)+reg
#pragma unroll
  for (int m = 0; m < 4; ++m) {
    size_t row0 = brow + wr + m * 16 + rg * 4;
#pragma unroll
    for (int n = 0; n < 4; ++n) {
      size_t col = bcol + wc + n * 16 + rr;
      float bv = 0.0f;
      if constexpr (HASBIAS) bv = bias[col];
#pragma unroll
      for (int r = 0; r < 4; ++r) {
        float v = acc[m][n][r] + bv;
        if constexpr (DOGELU) v = gelu_f(v);
        C[(row0 + r) * N + col] = f2b(v);
      }
    }
  }
}

// ------------------- launch -------------------

extern "C" void kernel_launch(void* const* d_in, const int* in_sizes, int n_in,
                              void* d_out, int out_size, void* d_ws, size_t ws_size,
                              hipStream_t stream) {
  const float* x = (const float*)d_in[0];
  const int* ei = (const int*)d_in[1];
  const float* W1 = (const float*)d_in[2]; const float* b1 = (const float*)d_in[3];
  const float* W2 = (const float*)d_in[4]; const float* b2 = (const float*)d_in[5];
  const float* W3 = (const float*)d_in[6]; const float* b3 = (const float*)d_in[7];
  const float* W4 = (const float*)d_in[8]; const float* b4 = (const float*)d_in[9];

  const int Nn = in_sizes[0] / 128;   // 100000
  const int E = in_sizes[1] / 2;      // 500000
  const int Mpad = (Nn + 127) & ~127; // 100096

  char* p = (char*)d_ws;
  auto alloc = [&](size_t bytes) {
    char* r = p;
    p += (bytes + 255) & ~(size_t)255;
    return r;
  };
  float* dinv = (float*)alloc((size_t)Nn * 4);
  int* cnt = (int*)alloc((size_t)Nn * 4);
  int* rowstart = (int*)alloc((size_t)(Nn + 1) * 4);
  int* cursor = (int*)alloc((size_t)Nn * 4);
  int* ssrc = (int*)alloc((size_t)E * 4);
  float* snorm = (float*)alloc((size_t)E * 4);
  unsigned short* WT1 = (unsigned short*)alloc((size_t)512 * 128 * 2);
  unsigned short* WT2 = (unsigned short*)alloc((size_t)768 * 512 * 2);
  unsigned short* WT3 = (unsigned short*)alloc((size_t)512 * 768 * 2);
  unsigned short* WT4 = (unsigned short*)alloc((size_t)128 * 512 * 2);
  unsigned short* bufA = (unsigned short*)alloc((size_t)Mpad * 512 * 2);
  unsigned short* bufB = (unsigned short*)alloc((size_t)Mpad * 768 * 2);

  const int EB = (E + 255) / 256;
  const int NB = (Nn + 255) / 256;
  const int AGGB = (Nn + 3) / 4;
  const int MT = Mpad / 128;

  hipMemsetAsync(cnt, 0, (size_t)Nn * 4, stream);
  count_kernel<<<EB, 256, 0, stream>>>(ei, E, cnt);
  dinv_kernel<<<NB, 256, 0, stream>>>(cnt, dinv, Nn);
  scan_kernel<<<1, 1024, 0, stream>>>(cnt, rowstart, cursor, Nn);
  fill_kernel<<<EB, 256, 0, stream>>>(ei, E, dinv, cursor, ssrc, snorm);
  wtrans_kernel<<<(128 * 512 + 255) / 256, 256, 0, stream>>>(W1, WT1, 128, 512);
  wtrans_kernel<<<(512 * 768 + 255) / 256, 256, 0, stream>>>(W2, WT2, 512, 768);
  wtrans_kernel<<<(768 * 512 + 255) / 256, 256, 0, stream>>>(W3, WT3, 768, 512);
  wtrans_kernel<<<(512 * 128 + 255) / 256, 256, 0, stream>>>(W4, WT4, 512, 128);

  // L1: a1 = Ahat @ x (f32 in, bf16 out, F=128); h1 = gelu(a1@W1 + b1)
  agg_kernel<128, true, false, false, false><<<AGGB, 256, 0, stream>>>(
      rowstart, ssrc, snorm, dinv, x, nullptr, bufA, Nn);
  gemm_bt<true, true><<<dim3(MT, 4), 256, 0, stream>>>(bufA, WT1, b1, bufB, 512, 128);

  // L2: a2 = Ahat @ h1 (F=512); h2 = gelu(a2@W2 + b2)
  agg_kernel<512, false, false, false, false><<<AGGB, 256, 0, stream>>>(
      rowstart, ssrc, snorm, dinv, bufB, nullptr, bufA, Nn);
  gemm_bt<true, true><<<dim3(MT, 6), 256, 0, stream>>>(bufA, WT2, b2, bufB, 768, 512);

  // L3: g3 = h2@W3 (no epi); h3 = gelu(Ahat@g3 + b3)
  gemm_bt<false, false><<<dim3(MT, 4), 256, 0, stream>>>(bufB, WT3, nullptr, bufA, 512, 768);
  agg_kernel<512, false, false, true, true><<<AGGB, 256, 0, stream>>>(
      rowstart, ssrc, snorm, dinv, bufA, b3, bufB, Nn);

  // L4: g4 = h3@W4 (no epi); out = Ahat@g4 + b4 (f32 out)
  gemm_bt<false, false><<<dim3(MT, 1), 256, 0, stream>>>(bufB, WT4, nullptr, bufA, 128, 512);
  agg_kernel<128, false, true, true, false><<<AGGB, 256, 0, stream>>>(
      rowstart, ssrc, snorm, dinv, bufA, b4, d_out, Nn);
}

// Round 2
// 781.610 us; speedup vs baseline: 1.3064x; 1.3064x over previous
//
#include <hip/hip_runtime.h>

typedef short bf16x8 __attribute__((ext_vector_type(8)));
typedef float f32x4 __attribute__((ext_vector_type(4)));

__device__ __forceinline__ float b2f(unsigned short u) {
  union { unsigned int i; float f; } x; x.i = ((unsigned int)u) << 16; return x.f;
}
__device__ __forceinline__ unsigned short f2b(float f) {
  union { float f; unsigned int u; } x; x.f = f;
  unsigned int r = (x.u + 0x7FFFu + ((x.u >> 16) & 1u)) >> 16;
  return (unsigned short)r;
}
__device__ __forceinline__ float gelu_f(float v) {
  return 0.5f * v * (1.0f + erff(v * 0.70710678118654752440f));
}

// ------------------- setup kernels -------------------

__global__ void count_kernel(const int* __restrict__ ei, int E, int* __restrict__ cnt) {
  int e = blockIdx.x * 256 + threadIdx.x;
  if (e < E) atomicAdd(&cnt[ei[E + e]], 1);
}

__global__ void dinv_kernel(const int* __restrict__ cnt, float* __restrict__ dinv, int Nn) {
  int n = blockIdx.x * 256 + threadIdx.x;
  if (n < Nn) dinv[n] = rsqrtf((float)cnt[n] + 1.0f);  // +1 self-loop
}

// ---- multi-block exclusive scan of cnt[0..Nn) -> rowstart/cursor (3 passes) ----
// 512 elements per block (256 threads x 2).

__global__ __launch_bounds__(256) void scanA_kernel(const int* __restrict__ cnt,
                                                    int* __restrict__ bsum, int Nn) {
  __shared__ int red[256];
  const int t = threadIdx.x;
  const int base = blockIdx.x * 512 + t * 2;
  int a = (base < Nn) ? cnt[base] : 0;
  int b = (base + 1 < Nn) ? cnt[base + 1] : 0;
  red[t] = a + b;
  __syncthreads();
  for (int d = 128; d > 0; d >>= 1) {
    if (t < d) red[t] += red[t + d];
    __syncthreads();
  }
  if (t == 0) bsum[blockIdx.x] = red[0];
}

__global__ __launch_bounds__(256) void scanB_kernel(const int* __restrict__ bsum,
                                                    int* __restrict__ boff,
                                                    int* __restrict__ rowstart,
                                                    int NBLK, int Nn) {
  __shared__ int sh[256];
  const int t = threadIdx.x;
  sh[t] = (t < NBLK) ? bsum[t] : 0;
  __syncthreads();
  for (int d = 1; d < 256; d <<= 1) {
    int x = sh[t];
    int add = (t >= d) ? sh[t - d] : 0;
    __syncthreads();
    sh[t] = x + add;
    __syncthreads();
  }
  if (t < NBLK) boff[t] = (t == 0) ? 0 : sh[t - 1];
  if (t == NBLK - 1) rowstart[Nn] = sh[t];
}

__global__ __launch_bounds__(256) void scanC_kernel(const int* __restrict__ cnt,
                                                    const int* __restrict__ boff,
                                                    int* __restrict__ rowstart,
                                                    int* __restrict__ cursor, int Nn) {
  __shared__ int sh[256];
  const int t = threadIdx.x;
  const int base = blockIdx.x * 512 + t * 2;
  int a = (base < Nn) ? cnt[base] : 0;
  int b = (base + 1 < Nn) ? cnt[base + 1] : 0;
  sh[t] = a + b;
  __syncthreads();
  for (int d = 1; d < 256; d <<= 1) {
    int x = sh[t];
    int add = (t >= d) ? sh[t - d] : 0;
    __syncthreads();
    sh[t] = x + add;
    __syncthreads();
  }
  const int off = boff[blockIdx.x] + ((t == 0) ? 0 : sh[t - 1]);
  if (base < Nn) { rowstart[base] = off; cursor[base] = off; }
  if (base + 1 < Nn) { rowstart[base + 1] = off + a; cursor[base + 1] = off + a; }
}

__global__ void fill_kernel(const int* __restrict__ ei, int E, const float* __restrict__ dinv,
                            int* __restrict__ cursor, int* __restrict__ ssrc,
                            float* __restrict__ snorm) {
  int e = blockIdx.x * 256 + threadIdx.x;
  if (e < E) {
    int s = ei[e], d = ei[E + e];
    int pos = atomicAdd(&cursor[d], 1);
    ssrc[pos] = s;
    snorm[pos] = dinv[s] * dinv[d];
  }
}

// W (K x N, f32, row-major) -> WT (N x K, bf16, row-major)
__global__ void wtrans_kernel(const float* __restrict__ W, unsigned short* __restrict__ WT,
                              int K, int N) {
  int i = blockIdx.x * 256 + threadIdx.x;
  if (i < K * N) {
    int n = i / K, k = i - n * K;
    WT[i] = f2b(W[k * N + n]);
  }
}

// ------------------- aggregation: out[n] = dinv[n]^2*in[n] + sum_e norm_e*in[src_e] -------------------
// one wave per node; V = F/64 elems per lane

template <int F, bool INF32, bool OUTF32, bool HASBIAS, bool DOGELU>
__global__ __launch_bounds__(256) void agg_kernel(
    const int* __restrict__ rowstart, const int* __restrict__ ssrc,
    const float* __restrict__ snorm, const float* __restrict__ dinv,
    const void* __restrict__ inv, const float* __restrict__ bias,
    void* __restrict__ outv, int Nn) {
  constexpr int V = F / 64;
  const int lane = threadIdx.x & 63;
  const int node = blockIdx.x * 4 + (threadIdx.x >> 6);
  if (node >= Nn) return;
  const int base = lane * V;
  float acc[V];
  {
    float w = dinv[node]; w = w * w;
    if constexpr (INF32) {
      const float* in = (const float*)inv + (size_t)node * F + base;
      if constexpr (V == 2) {
        float2 v = *(const float2*)in; acc[0] = w * v.x; acc[1] = w * v.y;
      } else {
        float4 v0 = *(const float4*)in; float4 v1 = *(const float4*)(in + 4);
        acc[0] = w * v0.x; acc[1] = w * v0.y; acc[2] = w * v0.z; acc[3] = w * v0.w;
        acc[4] = w * v1.x; acc[5] = w * v1.y; acc[6] = w * v1.z; acc[7] = w * v1.w;
      }
    } else {
      const unsigned short* in = (const unsigned short*)inv + (size_t)node * F + base;
      if constexpr (V == 2) {
        unsigned int v = *(const unsigned int*)in;
        acc[0] = w * b2f(v & 0xffffu); acc[1] = w * b2f(v >> 16);
      } else {
        bf16x8 v = *(const bf16x8*)in;
#pragma unroll
        for (int i = 0; i < 8; ++i) acc[i] = w * b2f((unsigned short)v[i]);
      }
    }
  }
  const int e0 = rowstart[node], e1 = rowstart[node + 1];
  for (int e = e0; e < e1; ++e) {
    const int s = ssrc[e];
    const float w = snorm[e];
    if constexpr (INF32) {
      const float* in = (const float*)inv + (size_t)s * F + base;
      if constexpr (V == 2) {
        float2 v = *(const float2*)in; acc[0] += w * v.x; acc[1] += w * v.y;
      } else {
        float4 v0 = *(const float4*)in; float4 v1 = *(const float4*)(in + 4);
        acc[0] += w * v0.x; acc[1] += w * v0.y; acc[2] += w * v0.z; acc[3] += w * v0.w;
        acc[4] += w * v1.x; acc[5] += w * v1.y; acc[6] += w * v1.z; acc[7] += w * v1.w;
      }
    } else {
      const unsigned short* in = (const unsigned short*)inv + (size_t)s * F + base;
      if constexpr (V == 2) {
        unsigned int v = *(const unsigned int*)in;
        acc[0] += w * b2f(v & 0xffffu); acc[1] += w * b2f(v >> 16);
      } else {
        bf16x8 v = *(const bf16x8*)in;
#pragma unroll
        for (int i = 0; i < 8; ++i) acc[i] += w * b2f((unsigned short)v[i]);
      }
    }
  }
  if constexpr (HASBIAS) {
#pragma unroll
    for (int i = 0; i < V; ++i) acc[i] += bias[base + i];
  }
  if constexpr (DOGELU) {
#pragma unroll
    for (int i = 0; i < V; ++i) acc[i] = gelu_f(acc[i]);
  }
  if constexpr (OUTF32) {
    float* out = (float*)outv + (size_t)node * F + base;
#pragma unroll
    for (int i = 0; i < V; ++i) out[i] = acc[i];
  } else {
    unsigned short* out = (unsigned short*)outv + (size_t)node * F + base;
    if constexpr (V == 2) {
      unsigned int pack = (unsigned int)f2b(acc[0]) | ((unsigned int)f2b(acc[1]) << 16);
      *(unsigned int*)out = pack;
    } else {
      bf16x8 o;
#pragma unroll
      for (int i = 0; i < 8; ++i) o[i] = (short)f2b(acc[i]);
      *(bf16x8*)out = o;
    }
  }
}

// ------------------- GEMM: C(M x N) = A(M x K) * BT(N x K)^T  [bf16 in, bf16 out] -------------------
// 128x128 tile, BK=32, 4 waves (2x2 of 64x64), mfma 16x16x32, global_load_lds staging.

template <bool HASBIAS, bool DOGELU>
__global__ __launch_bounds__(256) void gemm_bt(
    const unsigned short* __restrict__ A, const unsigned short* __restrict__ BT,
    const float* __restrict__ bias, unsigned short* __restrict__ C,
    int N, int K) {
  __shared__ alignas(16) unsigned short Asl[128 * 32];
  __shared__ alignas(16) unsigned short Bsl[128 * 32];
  const int tid = threadIdx.x;
  const int lane = tid & 63;
  const int wid = tid >> 6;
  const size_t brow = (size_t)blockIdx.x * 128;
  const size_t bcol = (size_t)blockIdx.y * 128;
  const int wr = (wid >> 1) * 64;
  const int wc = (wid & 1) * 64;
  const int rr = lane & 15, rg = lane >> 4;
  f32x4 acc[4][4] = {};
  const int KT = K >> 5;
  for (int kt = 0; kt < KT; ++kt) {
    const int kb = kt << 5;
#pragma unroll
    for (int rsub = 0; rsub < 2; ++rsub) {
      const int c = tid + rsub * 256;
      const int arow = c >> 2;
      const int acol = (c & 3) << 3;
      const unsigned short* gA = A + (brow + arow) * K + kb + acol;
      __builtin_amdgcn_global_load_lds((const __attribute__((address_space(1))) void*)gA,
                                       (__attribute__((address_space(3))) void*)(&Asl[c * 8]),
                                       16, 0, 0);
      const unsigned short* gB = BT + (bcol + arow) * K + kb + acol;
      __builtin_amdgcn_global_load_lds((const __attribute__((address_space(1))) void*)gB,
                                       (__attribute__((address_space(3))) void*)(&Bsl[c * 8]),
                                       16, 0, 0);
    }
    __syncthreads();
    bf16x8 af[4], bfr[4];
#pragma unroll
    for (int m = 0; m < 4; ++m) af[m] = *(const bf16x8*)(&Asl[(wr + m * 16 + rr) * 32 + rg * 8]);
#pragma unroll
    for (int n = 0; n < 4; ++n) bfr[n] = *(const bf16x8*)(&Bsl[(wc + n * 16 + rr) * 32 + rg * 8]);
#pragma unroll
    for (int m = 0; m < 4; ++m)
#pragma unroll
      for (int n = 0; n < 4; ++n)
        acc[m][n] = __builtin_amdgcn_mfma_f32_16x16x32_bf16(af[m], bfr[n], acc[m][n], 0, 0, 0);
    __syncthreads();
  }
  // C/D layout (m89): col = lane&15, row = 4*(lane>>4)+reg
#pragma unroll
  for (int m = 0; m < 4; ++m) {
    size_t row0 = brow + wr + m * 16 + rg * 4;
#pragma unroll
    for (int n = 0; n < 4; ++n) {
      size_t col = bcol + wc + n * 16 + rr;
      float bv = 0.0f;
      if constexpr (HASBIAS) bv = bias[col];
#pragma unroll
      for (int r = 0; r < 4; ++r) {
        float v = acc[m][n][r] + bv;
        if constexpr (DOGELU) v = gelu_f(v);
        C[(row0 + r) * N + col] = f2b(v);
      }
    }
  }
}

// ------------------- launch -------------------

extern "C" void kernel_launch(void* const* d_in, const int* in_sizes, int n_in,
                              void* d_out, int out_size, void* d_ws, size_t ws_size,
                              hipStream_t stream) {
  const float* x = (const float*)d_in[0];
  const int* ei = (const int*)d_in[1];
  const float* W1 = (const float*)d_in[2]; const float* b1 = (const float*)d_in[3];
  const float* W2 = (const float*)d_in[4]; const float* b2 = (const float*)d_in[5];
  const float* W3 = (const float*)d_in[6]; const float* b3 = (const float*)d_in[7];
  const float* W4 = (const float*)d_in[8]; const float* b4 = (const float*)d_in[9];

  const int Nn = in_sizes[0] / 128;   // 100000
  const int E = in_sizes[1] / 2;      // 500000
  const int Mpad = (Nn + 127) & ~127; // 100096

  char* p = (char*)d_ws;
  auto alloc = [&](size_t bytes) {
    char* r = p;
    p += (bytes + 255) & ~(size_t)255;
    return r;
  };
  float* dinv = (float*)alloc((size_t)Nn * 4);
  int* cnt = (int*)alloc((size_t)Nn * 4);
  int* rowstart = (int*)alloc((size_t)(Nn + 1) * 4);
  int* cursor = (int*)alloc((size_t)Nn * 4);
  int* ssrc = (int*)alloc((size_t)E * 4);
  float* snorm = (float*)alloc((size_t)E * 4);
  int* bsum = (int*)alloc((size_t)256 * 4);
  int* boff = (int*)alloc((size_t)256 * 4);
  unsigned short* WT1 = (unsigned short*)alloc((size_t)512 * 128 * 2);
  unsigned short* WT2 = (unsigned short*)alloc((size_t)768 * 512 * 2);
  unsigned short* WT3 = (unsigned short*)alloc((size_t)512 * 768 * 2);
  unsigned short* WT4 = (unsigned short*)alloc((size_t)128 * 512 * 2);
  unsigned short* bufA = (unsigned short*)alloc((size_t)Mpad * 512 * 2);
  unsigned short* bufB = (unsigned short*)alloc((size_t)Mpad * 768 * 2);

  const int EB = (E + 255) / 256;
  const int NB = (Nn + 255) / 256;
  const int AGGB = (Nn + 3) / 4;
  const int MT = Mpad / 128;
  const int NSCAN = (Nn + 511) / 512;  // 196 <= 256

  hipMemsetAsync(cnt, 0, (size_t)Nn * 4, stream);
  count_kernel<<<EB, 256, 0, stream>>>(ei, E, cnt);
  dinv_kernel<<<NB, 256, 0, stream>>>(cnt, dinv, Nn);
  scanA_kernel<<<NSCAN, 256, 0, stream>>>(cnt, bsum, Nn);
  scanB_kernel<<<1, 256, 0, stream>>>(bsum, boff, rowstart, NSCAN, Nn);
  scanC_kernel<<<NSCAN, 256, 0, stream>>>(cnt, boff, rowstart, cursor, Nn);
  fill_kernel<<<EB, 256, 0, stream>>>(ei, E, dinv, cursor, ssrc, snorm);
  wtrans_kernel<<<(128 * 512 + 255) / 256, 256, 0, stream>>>(W1, WT1, 128, 512);
  wtrans_kernel<<<(512 * 768 + 255) / 256, 256, 0, stream>>>(W2, WT2, 512, 768);
  wtrans_kernel<<<(768 * 512 + 255) / 256, 256, 0, stream>>>(W3, WT3, 768, 512);
  wtrans_kernel<<<(512 * 128 + 255) / 256, 256, 0, stream>>>(W4, WT4, 512, 128);

  // L1: a1 = Ahat @ x (f32 in, bf16 out, F=128); h1 = gelu(a1@W1 + b1)
  agg_kernel<128, true, false, false, false><<<AGGB, 256, 0, stream>>>(
      rowstart, ssrc, snorm, dinv, x, nullptr, bufA, Nn);
  gemm_bt<true, true><<<dim3(MT, 4), 256, 0, stream>>>(bufA, WT1, b1, bufB, 512, 128);

  // L2: a2 = Ahat @ h1 (F=512); h2 = gelu(a2@W2 + b2)
  agg_kernel<512, false, false, false, false><<<AGGB, 256, 0, stream>>>(
      rowstart, ssrc, snorm, dinv, bufB, nullptr, bufA, Nn);
  gemm_bt<true, true><<<dim3(MT, 6), 256, 0, stream>>>(bufA, WT2, b2, bufB, 768, 512);

  // L3: g3 = h2@W3 (no epi); h3 = gelu(Ahat@g3 + b3)
  gemm_bt<false, false><<<dim3(MT, 4), 256, 0, stream>>>(bufB, WT3, nullptr, bufA, 512, 768);
  agg_kernel<512, false, false, true, true><<<AGGB, 256, 0, stream>>>(
      rowstart, ssrc, snorm, dinv, bufA, b3, bufB, Nn);

  // L4: g4 = h3@W4 (no epi); out = Ahat@g4 + b4 (f32 out)
  gemm_bt<false, false><<<dim3(MT, 1), 256, 0, stream>>>(bufB, WT4, nullptr, bufA, 128, 512);
  agg_kernel<128, false, true, true, false><<<AGGB, 256, 0, stream>>>(
      rowstart, ssrc, snorm, dinv, bufA, b4, d_out, Nn);
}

// Round 3
// 759.710 us; speedup vs baseline: 1.3441x; 1.0288x over previous
//
#include <hip/hip_runtime.h>

typedef short bf16x8 __attribute__((ext_vector_type(8)));
typedef float f32x4 __attribute__((ext_vector_type(4)));

__device__ __forceinline__ float b2f(unsigned short u) {
  union { unsigned int i; float f; } x; x.i = ((unsigned int)u) << 16; return x.f;
}
__device__ __forceinline__ unsigned short f2b(float f) {
  union { float f; unsigned int u; } x; x.f = f;
  unsigned int r = (x.u + 0x7FFFu + ((x.u >> 16) & 1u)) >> 16;
  return (unsigned short)r;
}
__device__ __forceinline__ float gelu_f(float v) {
  return 0.5f * v * (1.0f + erff(v * 0.70710678118654752440f));
}

// ------------------- setup kernels -------------------

__global__ void count_kernel(const int* __restrict__ ei, int E, int* __restrict__ cnt) {
  int e = blockIdx.x * 256 + threadIdx.x;
  if (e < E) atomicAdd(&cnt[ei[E + e]], 1);
}

__global__ void dinv_kernel(const int* __restrict__ cnt, float* __restrict__ dinv, int Nn) {
  int n = blockIdx.x * 256 + threadIdx.x;
  if (n < Nn) dinv[n] = rsqrtf((float)cnt[n] + 1.0f);  // +1 self-loop
}

// ---- multi-block exclusive scan of cnt[0..Nn) -> rowstart/cursor (3 passes) ----

__global__ __launch_bounds__(256) void scanA_kernel(const int* __restrict__ cnt,
                                                    int* __restrict__ bsum, int Nn) {
  __shared__ int red[256];
  const int t = threadIdx.x;
  const int base = blockIdx.x * 512 + t * 2;
  int a = (base < Nn) ? cnt[base] : 0;
  int b = (base + 1 < Nn) ? cnt[base + 1] : 0;
  red[t] = a + b;
  __syncthreads();
  for (int d = 128; d > 0; d >>= 1) {
    if (t < d) red[t] += red[t + d];
    __syncthreads();
  }
  if (t == 0) bsum[blockIdx.x] = red[0];
}

__global__ __launch_bounds__(256) void scanB_kernel(const int* __restrict__ bsum,
                                                    int* __restrict__ boff,
                                                    int* __restrict__ rowstart,
                                                    int NBLK, int Nn) {
  __shared__ int sh[256];
  const int t = threadIdx.x;
  sh[t] = (t < NBLK) ? bsum[t] : 0;
  __syncthreads();
  for (int d = 1; d < 256; d <<= 1) {
    int x = sh[t];
    int add = (t >= d) ? sh[t - d] : 0;
    __syncthreads();
    sh[t] = x + add;
    __syncthreads();
  }
  if (t < NBLK) boff[t] = (t == 0) ? 0 : sh[t - 1];
  if (t == NBLK - 1) rowstart[Nn] = sh[t];
}

__global__ __launch_bounds__(256) void scanC_kernel(const int* __restrict__ cnt,
                                                    const int* __restrict__ boff,
                                                    int* __restrict__ rowstart,
                                                    int* __restrict__ cursor, int Nn) {
  __shared__ int sh[256];
  const int t = threadIdx.x;
  const int base = blockIdx.x * 512 + t * 2;
  int a = (base < Nn) ? cnt[base] : 0;
  int b = (base + 1 < Nn) ? cnt[base + 1] : 0;
  sh[t] = a + b;
  __syncthreads();
  for (int d = 1; d < 256; d <<= 1) {
    int x = sh[t];
    int add = (t >= d) ? sh[t - d] : 0;
    __syncthreads();
    sh[t] = x + add;
    __syncthreads();
  }
  const int off = boff[blockIdx.x] + ((t == 0) ? 0 : sh[t - 1]);
  if (base < Nn) { rowstart[base] = off; cursor[base] = off; }
  if (base + 1 < Nn) { rowstart[base + 1] = off + a; cursor[base + 1] = off + a; }
}

__global__ void fill_kernel(const int* __restrict__ ei, int E, const float* __restrict__ dinv,
                            int* __restrict__ cursor, int* __restrict__ ssrc,
                            float* __restrict__ snorm) {
  int e = blockIdx.x * 256 + threadIdx.x;
  if (e < E) {
    int s = ei[e], d = ei[E + e];
    int pos = atomicAdd(&cursor[d], 1);
    ssrc[pos] = s;
    snorm[pos] = dinv[s] * dinv[d];
  }
}

// W (K x N, f32, row-major) -> WT (N x K, bf16, row-major)
__global__ void wtrans_kernel(const float* __restrict__ W, unsigned short* __restrict__ WT,
                              int K, int N) {
  int i = blockIdx.x * 256 + threadIdx.x;
  if (i < K * N) {
    int n = i / K, k = i - n * K;
    WT[i] = f2b(W[k * N + n]);
  }
}

// ------------------- aggregation: out[n] = dinv[n]^2*in[n] + sum_e norm_e*in[src_e] -------------------

template <int F, bool INF32, bool OUTF32, bool HASBIAS, bool DOGELU>
__global__ __launch_bounds__(256) void agg_kernel(
    const int* __restrict__ rowstart, const int* __restrict__ ssrc,
    const float* __restrict__ snorm, const float* __restrict__ dinv,
    const void* __restrict__ inv, const float* __restrict__ bias,
    void* __restrict__ outv, int Nn) {
  constexpr int V = F / 64;
  const int lane = threadIdx.x & 63;
  const int node = blockIdx.x * 4 + (threadIdx.x >> 6);
  if (node >= Nn) return;
  const int base = lane * V;
  float acc[V];
  {
    float w = dinv[node]; w = w * w;
    if constexpr (INF32) {
      const float* in = (const float*)inv + (size_t)node * F + base;
      if constexpr (V == 2) {
        float2 v = *(const float2*)in; acc[0] = w * v.x; acc[1] = w * v.y;
      } else {
        float4 v0 = *(const float4*)in; float4 v1 = *(const float4*)(in + 4);
        acc[0] = w * v0.x; acc[1] = w * v0.y; acc[2] = w * v0.z; acc[3] = w * v0.w;
        acc[4] = w * v1.x; acc[5] = w * v1.y; acc[6] = w * v1.z; acc[7] = w * v1.w;
      }
    } else {
      const unsigned short* in = (const unsigned short*)inv + (size_t)node * F + base;
      if constexpr (V == 2) {
        unsigned int v = *(const unsigned int*)in;
        acc[0] = w * b2f(v & 0xffffu); acc[1] = w * b2f(v >> 16);
      } else {
        bf16x8 v = *(const bf16x8*)in;
#pragma unroll
        for (int i = 0; i < 8; ++i) acc[i] = w * b2f((unsigned short)v[i]);
      }
    }
  }
  const int e0 = rowstart[node], e1 = rowstart[node + 1];
  for (int e = e0; e < e1; ++e) {
    const int s = ssrc[e];
    const float w = snorm[e];
    if constexpr (INF32) {
      const float* in = (const float*)inv + (size_t)s * F + base;
      if constexpr (V == 2) {
        float2 v = *(const float2*)in; acc[0] += w * v.x; acc[1] += w * v.y;
      } else {
        float4 v0 = *(const float4*)in; float4 v1 = *(const float4*)(in + 4);
        acc[0] += w * v0.x; acc[1] += w * v0.y; acc[2] += w * v0.z; acc[3] += w * v0.w;
        acc[4] += w * v1.x; acc[5] += w * v1.y; acc[6] += w * v1.z; acc[7] += w * v1.w;
      }
    } else {
      const unsigned short* in = (const unsigned short*)inv + (size_t)s * F + base;
      if constexpr (V == 2) {
        unsigned int v = *(const unsigned int*)in;
        acc[0] += w * b2f(v & 0xffffu); acc[1] += w * b2f(v >> 16);
      } else {
        bf16x8 v = *(const bf16x8*)in;
#pragma unroll
        for (int i = 0; i < 8; ++i) acc[i] += w * b2f((unsigned short)v[i]);
      }
    }
  }
  if constexpr (HASBIAS) {
#pragma unroll
    for (int i = 0; i < V; ++i) acc[i] += bias[base + i];
  }
  if constexpr (DOGELU) {
#pragma unroll
    for (int i = 0; i < V; ++i) acc[i] = gelu_f(acc[i]);
  }
  if constexpr (OUTF32) {
    float* out = (float*)outv + (size_t)node * F + base;
#pragma unroll
    for (int i = 0; i < V; ++i) out[i] = acc[i];
  } else {
    unsigned short* out = (unsigned short*)outv + (size_t)node * F + base;
    if constexpr (V == 2) {
      unsigned int pack = (unsigned int)f2b(acc[0]) | ((unsigned int)f2b(acc[1]) << 16);
      *(unsigned int*)out = pack;
    } else {
      bf16x8 o;
#pragma unroll
      for (int i = 0; i < 8; ++i) o[i] = (short)f2b(acc[i]);
      *(bf16x8*)out = o;
    }
  }
}

// ------------------- GEMM: C(M x N) = A(M x K) * BT(N x K)^T  [bf16 in, bf16 out] -------------------
// 128x128 tile, BK=32, 4 waves, mfma 16x16x32, global_load_lds staging.
// LDS tile [128][32] bf16 with slot swizzle: phys_slot = log_slot ^ ((row>>1)&3)
// (pre-swizzled global source + swizzled ds_read; linear global_load_lds dest — rule 21).
// 1-D grid, bijective XCD chunking (m204), y-fastest work order for A-panel L2 reuse.

template <bool HASBIAS, bool DOGELU>
__global__ __launch_bounds__(256) void gemm_bt(
    const unsigned short* __restrict__ A, const unsigned short* __restrict__ BT,
    const float* __restrict__ bias, unsigned short* __restrict__ C,
    int N, int K, int NT) {
  __shared__ alignas(16) unsigned short Asl[128 * 32];
  __shared__ alignas(16) unsigned short Bsl[128 * 32];
  const int tid = threadIdx.x;
  const int lane = tid & 63;
  const int wid = tid >> 6;

  // XCD-chunked bijective remap (m204), then y-fastest decode.
  const int G = gridDim.x;
  const int q = G >> 3, r = G & 7;
  const int xcd = blockIdx.x & 7, ii = blockIdx.x >> 3;
  const int w = (xcd < r ? xcd * (q + 1) : r * (q + 1) + (xcd - r) * q) + ii;
  const int bx = w / NT;
  const int by = w - bx * NT;

  const size_t brow = (size_t)bx * 128;
  const size_t bcol = (size_t)by * 128;
  const int wr = (wid >> 1) * 64;
  const int wc = (wid & 1) * 64;
  const int rr = lane & 15, rg = lane >> 4;
  f32x4 acc[4][4] = {};
  const int KT = K >> 5;
  for (int kt = 0; kt < KT; ++kt) {
    const int kb = kt << 5;
#pragma unroll
    for (int rsub = 0; rsub < 2; ++rsub) {
      const int c = tid + rsub * 256;
      const int arow = c >> 2;
      const int jlog = (c & 3) ^ ((arow >> 1) & 3);  // inverse-swizzled source slot
      const unsigned short* gA = A + (brow + arow) * K + kb + jlog * 8;
      __builtin_amdgcn_global_load_lds((const __attribute__((address_space(1))) void*)gA,
                                       (__attribute__((address_space(3))) void*)(&Asl[c * 8]),
                                       16, 0, 0);
      const unsigned short* gB = BT + (bcol + arow) * K + kb + jlog * 8;
      __builtin_amdgcn_global_load_lds((const __attribute__((address_space(1))) void*)gB,
                                       (__attribute__((address_space(3))) void*)(&Bsl[c * 8]),
                                       16, 0, 0);
    }
    __syncthreads();
    bf16x8 af[4], bfr[4];
#pragma unroll
    for (int m = 0; m < 4; ++m) {
      const int R = wr + m * 16 + rr;
      af[m] = *(const bf16x8*)(&Asl[R * 32 + ((rg ^ ((R >> 1) & 3)) * 8)]);
    }
#pragma unroll
    for (int n = 0; n < 4; ++n) {
      const int R = wc + n * 16 + rr;
      bfr[n] = *(const bf16x8*)(&Bsl[R * 32 + ((rg ^ ((R >> 1) & 3)) * 8)]);
    }
#pragma unroll
    for (int m = 0; m < 4; ++m)
#pragma unroll
      for (int n = 0; n < 4; ++n)
        acc[m][n] = __builtin_amdgcn_mfma_f32_16x16x32_bf16(af[m], bfr[n], acc[m][n], 0, 0, 0);
    __syncthreads();
  }
  // C/D layout (m89): col = lane&15, row = 4*(lane>>4)+reg
#pragma unroll
  for (int m = 0; m < 4; ++m) {
    size_t row0 = brow + wr + m * 16 + rg * 4;
#pragma unroll
    for (int n = 0; n < 4; ++n) {
      size_t col = bcol + wc + n * 16 + rr;
      float bv = 0.0f;
      if constexpr (HASBIAS) bv = bias[col];
#pragma unroll
      for (int r2 = 0; r2 < 4; ++r2) {
        float v = acc[m][n][r2] + bv;
        if constexpr (DOGELU) v = gelu_f(v);
        C[(row0 + r2) * N + col] = f2b(v);
      }
    }
  }
}

// ------------------- launch -------------------

extern "C" void kernel_launch(void* const* d_in, const int* in_sizes, int n_in,
                              void* d_out, int out_size, void* d_ws, size_t ws_size,
                              hipStream_t stream) {
  const float* x = (const float*)d_in[0];
  const int* ei = (const int*)d_in[1];
  const float* W1 = (const float*)d_in[2]; const float* b1 = (const float*)d_in[3];
  const float* W2 = (const float*)d_in[4]; const float* b2 = (const float*)d_in[5];
  const float* W3 = (const float*)d_in[6]; const float* b3 = (const float*)d_in[7];
  const float* W4 = (const float*)d_in[8]; const float* b4 = (const float*)d_in[9];

  const int Nn = in_sizes[0] / 128;   // 100000
  const int E = in_sizes[1] / 2;      // 500000
  const int Mpad = (Nn + 127) & ~127; // 100096

  char* p = (char*)d_ws;
  auto alloc = [&](size_t bytes) {
    char* r = p;
    p += (bytes + 255) & ~(size_t)255;
    return r;
  };
  float* dinv = (float*)alloc((size_t)Nn * 4);
  int* cnt = (int*)alloc((size_t)Nn * 4);
  int* rowstart = (int*)alloc((size_t)(Nn + 1) * 4);
  int* cursor = (int*)alloc((size_t)Nn * 4);
  int* ssrc = (int*)alloc((size_t)E * 4);
  float* snorm = (float*)alloc((size_t)E * 4);
  int* bsum = (int*)alloc((size_t)256 * 4);
  int* boff = (int*)alloc((size_t)256 * 4);
  unsigned short* WT1 = (unsigned short*)alloc((size_t)512 * 128 * 2);
  unsigned short* WT2 = (unsigned short*)alloc((size_t)768 * 512 * 2);
  unsigned short* WT3 = (unsigned short*)alloc((size_t)512 * 768 * 2);
  unsigned short* WT4 = (unsigned short*)alloc((size_t)128 * 512 * 2);
  unsigned short* bufA = (unsigned short*)alloc((size_t)Mpad * 512 * 2);
  unsigned short* bufB = (unsigned short*)alloc((size_t)Mpad * 768 * 2);

  const int EB = (E + 255) / 256;
  const int NB = (Nn + 255) / 256;
  const int AGGB = (Nn + 3) / 4;
  const int MT = Mpad / 128;
  const int NSCAN = (Nn + 511) / 512;  // 196 <= 256

  hipMemsetAsync(cnt, 0, (size_t)Nn * 4, stream);
  count_kernel<<<EB, 256, 0, stream>>>(ei, E, cnt);
  dinv_kernel<<<NB, 256, 0, stream>>>(cnt, dinv, Nn);
  scanA_kernel<<<NSCAN, 256, 0, stream>>>(cnt, bsum, Nn);
  scanB_kernel<<<1, 256, 0, stream>>>(bsum, boff, rowstart, NSCAN, Nn);
  scanC_kernel<<<NSCAN, 256, 0, stream>>>(cnt, boff, rowstart, cursor, Nn);
  fill_kernel<<<EB, 256, 0, stream>>>(ei, E, dinv, cursor, ssrc, snorm);
  wtrans_kernel<<<(128 * 512 + 255) / 256, 256, 0, stream>>>(W1, WT1, 128, 512);
  wtrans_kernel<<<(512 * 768 + 255) / 256, 256, 0, stream>>>(W2, WT2, 512, 768);
  wtrans_kernel<<<(768 * 512 + 255) / 256, 256, 0, stream>>>(W3, WT3, 768, 512);
  wtrans_kernel<<<(512 * 128 + 255) / 256, 256, 0, stream>>>(W4, WT4, 512, 128);

  // L1: a1 = Ahat @ x (f32 in, bf16 out, F=128); h1 = gelu(a1@W1 + b1)
  agg_kernel<128, true, false, false, false><<<AGGB, 256, 0, stream>>>(
      rowstart, ssrc, snorm, dinv, x, nullptr, bufA, Nn);
  gemm_bt<true, true><<<MT * 4, 256, 0, stream>>>(bufA, WT1, b1, bufB, 512, 128, 4);

  // L2: a2 = Ahat @ h1 (F=512); h2 = gelu(a2@W2 + b2)
  agg_kernel<512, false, false, false, false><<<AGGB, 256, 0, stream>>>(
      rowstart, ssrc, snorm, dinv, bufB, nullptr, bufA, Nn);
  gemm_bt<true, true><<<MT * 6, 256, 0, stream>>>(bufA, WT2, b2, bufB, 768, 512, 6);

  // L3: g3 = h2@W3 (no epi); h3 = gelu(Ahat@g3 + b3)
  gemm_bt<false, false><<<MT * 4, 256, 0, stream>>>(bufB, WT3, nullptr, bufA, 512, 768, 4);
  agg_kernel<512, false, false, true, true><<<AGGB, 256, 0, stream>>>(
      rowstart, ssrc, snorm, dinv, bufA, b3, bufB, Nn);

  // L4: g4 = h3@W4 (no epi); out = Ahat@g4 + b4 (f32 out)
  gemm_bt<false, false><<<MT * 1, 256, 0, stream>>>(bufB, WT4, nullptr, bufA, 128, 512, 1);
  agg_kernel<128, false, true, true, false><<<AGGB, 256, 0, stream>>>(
      rowstart, ssrc, snorm, dinv, bufA, b4, d_out, Nn);
}